// Round 6
// baseline (296.574 us; speedup 1.0000x reference)
//
#include <hip/hip_runtime.h>
#include <math.h>

using u16 = unsigned short;
using u32 = unsigned int;

namespace {
constexpr int Hdim = 128;
constexpr int Pn = 50000;
constexpr int Cn = 20000;
constexpr int Bn = 4;
constexpr int NClause = Bn * Cn;   // 80000
constexpr int NRows = Bn * Pn;     // 200000
constexpr int CAP = 64;            // max clauses per variable (mean deg 4.8; P(>=64) ~ e^-150)
}

typedef __attribute__((ext_vector_type(4))) float f32x4;
typedef __attribute__((ext_vector_type(8))) short bf16x8;

static __device__ __forceinline__ float bf2f(u16 v) {
    u32 u = ((u32)v) << 16;
    return __builtin_bit_cast(float, u);
}
static __device__ __forceinline__ u16 f2bf(float f) {
    u32 u = __builtin_bit_cast(u32, f);
    u32 r = u + 0x7FFFu + ((u >> 16) & 1u);
    return (u16)(r >> 16);
}

// ONE setup kernel: per-row redundant weight-chain (no inter-stage sync needed),
// packs Wcomb and W_s1 into MFMA B-frag layout, folds bias, zeros cursor.
// Block o handles output row o of Wcomb = W_cv*W_ce*W_vc.
__global__ __launch_bounds__(128) void setup_kernel(
    const float* __restrict__ W_vc, const float* __restrict__ b_vc,
    const float* __restrict__ W_ce, const float* __restrict__ b_ce,
    const float* __restrict__ W_cv, const float* __restrict__ b_cv,
    const float* __restrict__ W_s1,
    u16* __restrict__ WcombPack, u16* __restrict__ Ws1Pack,
    float* __restrict__ bias_comb, int* __restrict__ cursor) {
    int o = blockIdx.x, t = threadIdx.x;
    __shared__ float u[Hdim];
    __shared__ float red[Hdim];
    // u[t] = (row o of W_cv) . (col t of W_ce)
    float acc = 0.f;
#pragma unroll 8
    for (int h = 0; h < Hdim; ++h) acc = fmaf(W_cv[o * Hdim + h], W_ce[h * Hdim + t], acc);
    u[t] = acc;
    // b1[t] = (row t of W_ce) . b_vc + b_ce[t]
    float b1 = b_ce[t];
#pragma unroll 8
    for (int h = 0; h < Hdim; ++h) b1 = fmaf(W_ce[t * Hdim + h], b_vc[h], b1);
    red[t] = W_cv[o * Hdim + t] * b1;
    __syncthreads();
    // bias_comb[o] = sum_t red[t] + b_cv[o]
#pragma unroll
    for (int s = 64; s > 0; s >>= 1) {
        if (t < s) red[t] += red[t + s];
        __syncthreads();
    }
    if (t == 0) bias_comb[o] = red[0] + b_cv[o];
    // Wcomb[o][t] = u . (col t of W_vc)
    float w = 0.f;
#pragma unroll 8
    for (int h = 0; h < Hdim; ++h) w = fmaf(u[h], W_vc[h * Hdim + t], w);
    // pack element (n=o, k=t) into B-frag layout:
    // dst[((nt*4+ks)*64 + lane)*8 + j], lane = lofs*16 + (n&15)
    int nt = o >> 4, ks = t >> 5, lofs = (t >> 3) & 3, j = t & 7;
    int lane = lofs * 16 + (o & 15);
    size_t dst = (size_t)(((nt * 4 + ks) * 64 + lane)) * 8 + j;
    WcombPack[dst] = f2bf(w);
    Ws1Pack[dst] = f2bf(W_s1[o * Hdim + t]);
    // zero cursor
    for (int i = o * 128 + t; i < Pn; i += 128 * 128) cursor[i] = 0;
}

// bucketed CSR: entries[p*CAP + pos] = fid, cursor[p] = degree (first-occurrence dedup)
__global__ void fill_kernel(const int* __restrict__ ci, int* __restrict__ cursor,
                            int* __restrict__ entries) {
    int fid = blockIdx.x * blockDim.x + threadIdx.x;
    if (fid >= NClause) return;
    int i0 = ci[fid * 3 + 0], i1 = ci[fid * 3 + 1], i2 = ci[fid * 3 + 2];
    int pos = atomicAdd(&cursor[i0], 1);
    entries[i0 * CAP + pos] = fid;
    if (i1 != i0) { pos = atomicAdd(&cursor[i1], 1); entries[i1 * CAP + pos] = fid; }
    if (i2 != i0 && i2 != i1) { pos = atomicAdd(&cursor[i2], 1); entries[i2 * CAP + pos] = fid; }
}

// meanG[fid] = (1/3) * sum_k row[i_k]
// from_f32=1: rows from vs0[b*Pn + i] (fp32, batched); else from msgs[i] (bf16, shared)
__global__ __launch_bounds__(256) void cmean_kernel(const int* __restrict__ ci,
                                                    const float* __restrict__ vs0,
                                                    const u16* __restrict__ msgs,
                                                    u16* __restrict__ meanG, int from_f32) {
    int tid = threadIdx.x;
    int r = tid >> 4, gt = tid & 15;
    int fid = blockIdx.x * 16 + r;
    int i0 = ci[fid * 3 + 0], i1 = ci[fid * 3 + 1], i2 = ci[fid * 3 + 2];
    int co = gt * 8;
    float s[8];
    if (from_f32) {
        const float* base = vs0 + (size_t)(fid / Cn) * Pn * Hdim;
        const float* r0 = base + (size_t)i0 * Hdim + co;
        const float* r1 = base + (size_t)i1 * Hdim + co;
        const float* r2 = base + (size_t)i2 * Hdim + co;
        f32x4 a0 = *(const f32x4*)r0, a1 = *(const f32x4*)(r0 + 4);
        f32x4 b0 = *(const f32x4*)r1, b1 = *(const f32x4*)(r1 + 4);
        f32x4 c0 = *(const f32x4*)r2, c1 = *(const f32x4*)(r2 + 4);
#pragma unroll
        for (int j = 0; j < 4; ++j) {
            s[j] = a0[j] + b0[j] + c0[j];
            s[j + 4] = a1[j] + b1[j] + c1[j];
        }
    } else {
        bf16x8 v0 = *(const bf16x8*)(msgs + (size_t)i0 * Hdim + co);
        bf16x8 v1 = *(const bf16x8*)(msgs + (size_t)i1 * Hdim + co);
        bf16x8 v2 = *(const bf16x8*)(msgs + (size_t)i2 * Hdim + co);
#pragma unroll
        for (int j = 0; j < 8; ++j)
            s[j] = bf2f((u16)v0[j]) + bf2f((u16)v1[j]) + bf2f((u16)v2[j]);
    }
    bf16x8 o;
#pragma unroll
    for (int j = 0; j < 8; ++j) o[j] = (short)f2bf(s[j] * (1.f / 3.f));
    *(bf16x8*)(meanG + (size_t)fid * Hdim + co) = o;
}

// Fused per-variable aggregate + GEMM:
// iter0: A[p] = agg(meanG);          V1[p] = A[p];  msgs[p] = mask(W*A + bias)
// iter1: A[p] = V1[p] + agg(meanG);                 msgs[p] += mask(W*A + bias)
__global__ __launch_bounds__(256) void vagg_gemm_kernel(
    const u16* __restrict__ meanG, const int* __restrict__ counts,
    const int* __restrict__ entries, u16* __restrict__ V1,
    const u16* __restrict__ Bpack, const float* __restrict__ bias,
    u16* __restrict__ msgs, int iter) {
    __shared__ __align__(16) u16 Atile[64 * 136];
    __shared__ __align__(16) u16 Btile[128 * 128];
    int tid = threadIdx.x;
    int block0 = blockIdx.x * 64;
    {   // stage packed B (32KB)
        const bf16x8* s = (const bf16x8*)Bpack;
        bf16x8* d = (bf16x8*)Btile;
#pragma unroll
        for (int i = 0; i < 8; ++i) d[tid + i * 256] = s[tid + i * 256];
    }
    int wave = tid >> 6, lane = tid & 63;
    // phase 1: aggregate; wave handles 16 p's, lane covers cols [lane*2, lane*2+1]
    for (int s = 0; s < 16; ++s) {
        int r = wave * 16 + s;
        int p = block0 + r;
        float a0 = 0.f, a1 = 0.f;
        if (p < Pn) {
            int deg = counts[p];
            const int* ep = entries + p * CAP;
            for (int e = 0; e < deg; ++e) {
                int cid = ep[e];
                u32 v = *(const u32*)(meanG + (size_t)cid * Hdim + lane * 2);
                a0 += bf2f((u16)(v & 0xffffu));
                a1 += bf2f((u16)(v >> 16));
            }
            if (deg > 0) { float inv = 1.f / (float)deg; a0 *= inv; a1 *= inv; }
            u32* vp = (u32*)(V1 + (size_t)p * Hdim + lane * 2);
            if (iter == 0) {
                *vp = (u32)f2bf(a0) | ((u32)f2bf(a1) << 16);
            } else {
                u32 old = *vp;
                a0 += bf2f((u16)(old & 0xffffu));
                a1 += bf2f((u16)(old >> 16));
            }
        }
        *(u32*)&Atile[r * 136 + lane * 2] = (u32)f2bf(a0) | ((u32)f2bf(a1) << 16);
    }
    __syncthreads();
    // phase 2: MFMA
    int w = tid >> 6, l = tid & 63;
    int arow = w * 16 + (l & 15);
    int kofs = (l >> 4) * 8;
    f32x4 acc[8];
#pragma unroll
    for (int nt = 0; nt < 8; ++nt) acc[nt] = (f32x4){0.f, 0.f, 0.f, 0.f};
#pragma unroll
    for (int ks = 0; ks < 4; ++ks) {
        bf16x8 af = *(const bf16x8*)(&Atile[arow * 136 + ks * 32 + kofs]);
#pragma unroll
        for (int nt = 0; nt < 8; ++nt) {
            bf16x8 bfr = *(const bf16x8*)(&Btile[((nt * 4 + ks) * 64 + l) * 8]);
            acc[nt] = __builtin_amdgcn_mfma_f32_16x16x32_bf16(af, bfr, acc[nt], 0, 0, 0);
        }
    }
    __syncthreads();
    int crow = w * 16 + (l >> 4) * 4;
    int dg[4];
#pragma unroll
    for (int reg = 0; reg < 4; ++reg) {
        int p = block0 + crow + reg;
        dg[reg] = (p < Pn) ? counts[p] : 0;
    }
#pragma unroll
    for (int nt = 0; nt < 8; ++nt) {
        int col = nt * 16 + (l & 15);
        float bc = bias[col];
#pragma unroll
        for (int reg = 0; reg < 4; ++reg) {
            float val = acc[nt][reg] + bc;
            Atile[(crow + reg) * 136 + col] = f2bf(dg[reg] > 0 ? val : 0.f);
        }
    }
    __syncthreads();
#pragma unroll
    for (int pass = 0; pass < 4; ++pass) {
        int t = pass * 256 + tid;
        int r = t >> 4, seg = t & 15;
        int row = block0 + r;
        if (row < Pn) {
            bf16x8 o = *(const bf16x8*)(&Atile[r * 136 + seg * 8]);
            if (iter != 0) {
                bf16x8 pv = *(const bf16x8*)(msgs + (size_t)row * Hdim + seg * 8);
#pragma unroll
                for (int j = 0; j < 8; ++j)
                    o[j] = (short)f2bf(bf2f((u16)o[j]) + bf2f((u16)pv[j]));
            }
            *(bf16x8*)(msgs + (size_t)row * Hdim + seg * 8) = o;
        }
    }
}

// out[row] = sigmoid( W_s2 . relu( (vs0[row]+msgs[row%Pn]) * W_s1^T + b_s1 ) + b_s2 )
__global__ __launch_bounds__(256) void final_kernel(
    const float* __restrict__ vs0, const u16* __restrict__ msgs, const u16* __restrict__ Bpack,
    const float* __restrict__ b_s1, const float* __restrict__ W_s2, const float* __restrict__ b_s2,
    float* __restrict__ out) {
    __shared__ __align__(16) u16 Atile[64 * 136];
    __shared__ __align__(16) u16 Btile[128 * 128];
    int tid = threadIdx.x;
    int block0 = blockIdx.x * 64;
    {
        const bf16x8* s = (const bf16x8*)Bpack;
        bf16x8* d = (bf16x8*)Btile;
#pragma unroll
        for (int i = 0; i < 8; ++i) d[tid + i * 256] = s[tid + i * 256];
    }
#pragma unroll
    for (int pass = 0; pass < 4; ++pass) {
        int t = pass * 256 + tid;
        int r = t >> 4, seg = t & 15;
        int row = block0 + r;
        int p = row % Pn;
        int co = seg * 8;
        const float* vp = vs0 + (size_t)row * Hdim + co;
        f32x4 x = *(const f32x4*)vp, y = *(const f32x4*)(vp + 4);
        bf16x8 m = *(const bf16x8*)(msgs + (size_t)p * Hdim + co);
        bf16x8 o;
#pragma unroll
        for (int j = 0; j < 4; ++j) {
            o[j] = (short)f2bf(x[j] + bf2f((u16)m[j]));
            o[j + 4] = (short)f2bf(y[j] + bf2f((u16)m[j + 4]));
        }
        *(bf16x8*)(&Atile[r * 136 + seg * 8]) = o;
    }
    __syncthreads();
    int w = tid >> 6, l = tid & 63;
    int arow = w * 16 + (l & 15);
    int kofs = (l >> 4) * 8;
    f32x4 acc[8];
#pragma unroll
    for (int nt = 0; nt < 8; ++nt) acc[nt] = (f32x4){0.f, 0.f, 0.f, 0.f};
#pragma unroll
    for (int ks = 0; ks < 4; ++ks) {
        bf16x8 af = *(const bf16x8*)(&Atile[arow * 136 + ks * 32 + kofs]);
#pragma unroll
        for (int nt = 0; nt < 8; ++nt) {
            bf16x8 bfr = *(const bf16x8*)(&Btile[((nt * 4 + ks) * 64 + l) * 8]);
            acc[nt] = __builtin_amdgcn_mfma_f32_16x16x32_bf16(af, bfr, acc[nt], 0, 0, 0);
        }
    }
    float part[4] = {0.f, 0.f, 0.f, 0.f};
#pragma unroll
    for (int nt = 0; nt < 8; ++nt) {
        int col = nt * 16 + (l & 15);
        float b1 = b_s1[col], w2 = W_s2[col];
#pragma unroll
        for (int reg = 0; reg < 4; ++reg)
            part[reg] += fmaxf(acc[nt][reg] + b1, 0.f) * w2;
    }
#pragma unroll
    for (int m = 1; m < 16; m <<= 1)
#pragma unroll
        for (int reg = 0; reg < 4; ++reg) part[reg] += __shfl_xor(part[reg], m, 64);
    if ((l & 15) == 0) {
        float lb = b_s2[0];
        int row0 = block0 + w * 16 + (l >> 4) * 4;
#pragma unroll
        for (int reg = 0; reg < 4; ++reg)
            out[row0 + reg] = 1.f / (1.f + expf(-(part[reg] + lb)));
    }
}

extern "C" void kernel_launch(void* const* d_in, const int* in_sizes, int n_in,
                              void* d_out, int out_size, void* d_ws, size_t ws_size,
                              hipStream_t stream) {
    (void)in_sizes; (void)n_in; (void)out_size; (void)ws_size;
    const int* ci = (const int*)d_in[0];
    const float* vs0 = (const float*)d_in[1];
    const float* W_vc = (const float*)d_in[2];
    const float* b_vc = (const float*)d_in[3];
    const float* W_ce = (const float*)d_in[4];
    const float* b_ce = (const float*)d_in[5];
    const float* W_cv = (const float*)d_in[6];
    const float* b_cv = (const float*)d_in[7];
    const float* W_s1 = (const float*)d_in[8];
    const float* b_s1 = (const float*)d_in[9];
    const float* W_s2 = (const float*)d_in[10];
    const float* b_s2 = (const float*)d_in[11];
    float* out = (float*)d_out;

    char* ws = (char*)d_ws;
    size_t off = 0;
    auto alloc = [&](size_t bytes) -> void* {
        off = (off + 255) & ~(size_t)255;
        void* p = ws + off;
        off += bytes;
        return p;
    };
    float* bias_comb = (float*)alloc(Hdim * 4);
    u16* WcombPack = (u16*)alloc(Hdim * Hdim * 2);
    u16* Ws1Pack = (u16*)alloc(Hdim * Hdim * 2);
    int* cursor = (int*)alloc(Pn * 4);
    int* entries = (int*)alloc((size_t)Pn * CAP * 4);       // 12.8 MB bucketed CSR
    u16* meanG = (u16*)alloc((size_t)NClause * Hdim * 2);   // 20.5 MB
    u16* V1 = (u16*)alloc((size_t)Pn * Hdim * 2);           // 12.8 MB iter-1 aggregate
    u16* msgs = (u16*)alloc((size_t)Pn * Hdim * 2);         // 12.8 MB

    // 1. fused setup: weight fold + both packs + bias + cursor zero
    setup_kernel<<<Hdim, Hdim, 0, stream>>>(W_vc, b_vc, W_ce, b_ce, W_cv, b_cv, W_s1,
                                            WcombPack, Ws1Pack, bias_comb, cursor);
    // 2. bucketed CSR
    fill_kernel<<<(NClause + 255) / 256, 256, 0, stream>>>(ci, cursor, entries);

    int vg_grid = (Pn + 63) / 64;
    // 3-4. iter 1: meanG from fp32 vs0; V1 = agg; msgs1 = mask(W*V1 + b)
    cmean_kernel<<<NClause / 16, 256, 0, stream>>>(ci, vs0, nullptr, meanG, 1);
    vagg_gemm_kernel<<<vg_grid, 256, 0, stream>>>(meanG, cursor, entries, V1, WcombPack,
                                                  bias_comb, msgs, 0);
    // 5-6. iter 2: meanG from msgs1; A = V1 + agg; msgs2 = msgs1 + mask(W*A + b)
    cmean_kernel<<<NClause / 16, 256, 0, stream>>>(ci, nullptr, msgs, meanG, 0);
    vagg_gemm_kernel<<<vg_grid, 256, 0, stream>>>(meanG, cursor, entries, V1, WcombPack,
                                                  bias_comb, msgs, 1);
    // 7. readout
    final_kernel<<<NRows / 64, 256, 0, stream>>>(vs0, msgs, Ws1Pack, b_s1, W_s2, b_s2, out);
}

// Round 7
// 181.385 us; speedup vs baseline: 1.6351x; 1.6351x over previous
//
#include <hip/hip_runtime.h>
#include <math.h>

using u16 = unsigned short;
using u32 = unsigned int;

namespace {
constexpr int Hdim = 128;
constexpr int Pn = 50000;
constexpr int Cn = 20000;
constexpr int Bn = 4;
constexpr int NClause = Bn * Cn;   // 80000
constexpr int NRows = Bn * Pn;     // 200000
constexpr int CAP = 64;            // max clauses per variable (mean deg 4.8; P(>=64) ~ e^-150)
}

typedef __attribute__((ext_vector_type(4))) float f32x4;
typedef __attribute__((ext_vector_type(8))) short bf16x8;

static __device__ __forceinline__ float bf2f(u16 v) {
    u32 u = ((u32)v) << 16;
    return __builtin_bit_cast(float, u);
}
static __device__ __forceinline__ u16 f2bf(float f) {
    u32 u = __builtin_bit_cast(u32, f);
    u32 r = u + 0x7FFFu + ((u >> 16) & 1u);
    return (u16)(r >> 16);
}

// ONE setup kernel: per-row redundant weight-chain (no inter-stage sync needed),
// packs Wcomb and W_s1 into MFMA B-frag layout, folds bias, zeros cursor.
// Block o handles output row o of Wcomb = W_cv*W_ce*W_vc.
__global__ __launch_bounds__(128) void setup_kernel(
    const float* __restrict__ W_vc, const float* __restrict__ b_vc,
    const float* __restrict__ W_ce, const float* __restrict__ b_ce,
    const float* __restrict__ W_cv, const float* __restrict__ b_cv,
    const float* __restrict__ W_s1,
    u16* __restrict__ WcombPack, u16* __restrict__ Ws1Pack,
    float* __restrict__ bias_comb, int* __restrict__ cursor) {
    int o = blockIdx.x, t = threadIdx.x;
    __shared__ float u[Hdim];
    __shared__ float red[Hdim];
    float acc = 0.f;
#pragma unroll 8
    for (int h = 0; h < Hdim; ++h) acc = fmaf(W_cv[o * Hdim + h], W_ce[h * Hdim + t], acc);
    u[t] = acc;
    float b1 = b_ce[t];
#pragma unroll 8
    for (int h = 0; h < Hdim; ++h) b1 = fmaf(W_ce[t * Hdim + h], b_vc[h], b1);
    red[t] = W_cv[o * Hdim + t] * b1;
    __syncthreads();
#pragma unroll
    for (int s = 64; s > 0; s >>= 1) {
        if (t < s) red[t] += red[t + s];
        __syncthreads();
    }
    if (t == 0) bias_comb[o] = red[0] + b_cv[o];
    float w = 0.f;
#pragma unroll 8
    for (int h = 0; h < Hdim; ++h) w = fmaf(u[h], W_vc[h * Hdim + t], w);
    // pack element (n=o, k=t): dst[((nt*4+ks)*64 + lane)*8 + j], lane = lofs*16 + (n&15)
    int nt = o >> 4, ks = t >> 5, lofs = (t >> 3) & 3, j = t & 7;
    int lane = lofs * 16 + (o & 15);
    size_t dst = (size_t)(((nt * 4 + ks) * 64 + lane)) * 8 + j;
    WcombPack[dst] = f2bf(w);
    Ws1Pack[dst] = f2bf(W_s1[o * Hdim + t]);
    for (int i = o * 128 + t; i < Pn; i += 128 * 128) cursor[i] = 0;
}

// bucketed CSR: entries[p*CAP + pos] = fid, cursor[p] = degree (first-occurrence dedup)
__global__ void fill_kernel(const int* __restrict__ ci, int* __restrict__ cursor,
                            int* __restrict__ entries) {
    int fid = blockIdx.x * blockDim.x + threadIdx.x;
    if (fid >= NClause) return;
    int i0 = ci[fid * 3 + 0], i1 = ci[fid * 3 + 1], i2 = ci[fid * 3 + 2];
    int pos = atomicAdd(&cursor[i0], 1);
    entries[i0 * CAP + pos] = fid;
    if (i1 != i0) { pos = atomicAdd(&cursor[i1], 1); entries[i1 * CAP + pos] = fid; }
    if (i2 != i0 && i2 != i1) { pos = atomicAdd(&cursor[i2], 1); entries[i2 * CAP + pos] = fid; }
}

// meanG[fid] = (1/3) * sum_k row[i_k]
// from_f32=1: rows from vs0[b*Pn + i] (fp32, batched); else from msgs[i] (bf16, shared)
__global__ __launch_bounds__(256) void cmean_kernel(const int* __restrict__ ci,
                                                    const float* __restrict__ vs0,
                                                    const u16* __restrict__ msgs,
                                                    u16* __restrict__ meanG, int from_f32) {
    int tid = threadIdx.x;
    int r = tid >> 4, gt = tid & 15;
    int fid = blockIdx.x * 16 + r;
    int i0 = ci[fid * 3 + 0], i1 = ci[fid * 3 + 1], i2 = ci[fid * 3 + 2];
    int co = gt * 8;
    float s[8];
    if (from_f32) {
        const float* base = vs0 + (size_t)(fid / Cn) * Pn * Hdim;
        const float* r0 = base + (size_t)i0 * Hdim + co;
        const float* r1 = base + (size_t)i1 * Hdim + co;
        const float* r2 = base + (size_t)i2 * Hdim + co;
        f32x4 a0 = *(const f32x4*)r0, a1 = *(const f32x4*)(r0 + 4);
        f32x4 b0 = *(const f32x4*)r1, b1 = *(const f32x4*)(r1 + 4);
        f32x4 c0 = *(const f32x4*)r2, c1 = *(const f32x4*)(r2 + 4);
#pragma unroll
        for (int j = 0; j < 4; ++j) {
            s[j] = a0[j] + b0[j] + c0[j];
            s[j + 4] = a1[j] + b1[j] + c1[j];
        }
    } else {
        bf16x8 v0 = *(const bf16x8*)(msgs + (size_t)i0 * Hdim + co);
        bf16x8 v1 = *(const bf16x8*)(msgs + (size_t)i1 * Hdim + co);
        bf16x8 v2 = *(const bf16x8*)(msgs + (size_t)i2 * Hdim + co);
#pragma unroll
        for (int j = 0; j < 8; ++j)
            s[j] = bf2f((u16)v0[j]) + bf2f((u16)v1[j]) + bf2f((u16)v2[j]);
    }
    bf16x8 o;
#pragma unroll
    for (int j = 0; j < 8; ++j) o[j] = (short)f2bf(s[j] * (1.f / 3.f));
    *(bf16x8*)(meanG + (size_t)fid * Hdim + co) = o;
}

// V[p] = (add_base ? V[p] : 0) + (1/deg) * sum over bucket entries of meanG[fid]
// 12500 blocks x 4 waves, one wave per variable: gather needs TLP, not LDS tiles.
__global__ __launch_bounds__(256) void vagg_kernel(const u16* __restrict__ meanG,
                                                   const int* __restrict__ counts,
                                                   const int* __restrict__ entries,
                                                   u16* __restrict__ V, int add_base) {
    int wave = threadIdx.x >> 6, lane = threadIdx.x & 63;
    int p = blockIdx.x * 4 + wave;
    if (p >= Pn) return;
    int deg = counts[p];
    const int* ep = entries + p * CAP;
    float a0 = 0.f, a1 = 0.f;
    for (int e = 0; e < deg; ++e) {
        int cid = ep[e];
        u32 v = *(const u32*)(meanG + (size_t)cid * Hdim + lane * 2);
        a0 += bf2f((u16)(v & 0xffffu));
        a1 += bf2f((u16)(v >> 16));
    }
    if (deg > 0) { float inv = 1.f / (float)deg; a0 *= inv; a1 *= inv; }
    u32* vp = (u32*)(V + (size_t)p * Hdim + lane * 2);
    if (add_base) {
        u32 old = *vp;
        a0 += bf2f((u16)(old & 0xffffu));
        a1 += bf2f((u16)(old >> 16));
    }
    *vp = (u32)f2bf(a0) | ((u32)f2bf(a1) << 16);
}

// msgs[p] = (accum ? msgs[p] : 0) + (deg>0 ? W*V[p] + bias : 0)
__global__ __launch_bounds__(256) void gemm_kernel(const u16* __restrict__ Vin,
                                                   const u16* __restrict__ Bpack,
                                                   const float* __restrict__ bias,
                                                   const int* __restrict__ counts,
                                                   u16* __restrict__ msgs, int accum) {
    __shared__ __align__(16) u16 Atile[64 * 136];
    __shared__ __align__(16) u16 Btile[128 * 128];
    int tid = threadIdx.x;
    int block0 = blockIdx.x * 64;
    {
        const bf16x8* s = (const bf16x8*)Bpack;
        bf16x8* d = (bf16x8*)Btile;
#pragma unroll
        for (int i = 0; i < 8; ++i) d[tid + i * 256] = s[tid + i * 256];
    }
#pragma unroll
    for (int pass = 0; pass < 4; ++pass) {
        int t = pass * 256 + tid;
        int r = t >> 4, seg = t & 15;
        int row = block0 + r;
        bf16x8 o = (bf16x8){0, 0, 0, 0, 0, 0, 0, 0};
        if (row < Pn) o = *(const bf16x8*)(Vin + (size_t)row * Hdim + seg * 8);
        *(bf16x8*)(&Atile[r * 136 + seg * 8]) = o;
    }
    __syncthreads();
    int w = tid >> 6, l = tid & 63;
    int arow = w * 16 + (l & 15);
    int kofs = (l >> 4) * 8;
    f32x4 acc[8];
#pragma unroll
    for (int nt = 0; nt < 8; ++nt) acc[nt] = (f32x4){0.f, 0.f, 0.f, 0.f};
#pragma unroll
    for (int ks = 0; ks < 4; ++ks) {
        bf16x8 af = *(const bf16x8*)(&Atile[arow * 136 + ks * 32 + kofs]);
#pragma unroll
        for (int nt = 0; nt < 8; ++nt) {
            bf16x8 bfr = *(const bf16x8*)(&Btile[((nt * 4 + ks) * 64 + l) * 8]);
            acc[nt] = __builtin_amdgcn_mfma_f32_16x16x32_bf16(af, bfr, acc[nt], 0, 0, 0);
        }
    }
    __syncthreads();
    int crow = w * 16 + (l >> 4) * 4;
    int dg[4];
#pragma unroll
    for (int reg = 0; reg < 4; ++reg) {
        int p = block0 + crow + reg;
        dg[reg] = (p < Pn) ? counts[p] : 0;
    }
#pragma unroll
    for (int nt = 0; nt < 8; ++nt) {
        int col = nt * 16 + (l & 15);
        float bc = bias[col];
#pragma unroll
        for (int reg = 0; reg < 4; ++reg) {
            float val = acc[nt][reg] + bc;
            Atile[(crow + reg) * 136 + col] = f2bf(dg[reg] > 0 ? val : 0.f);
        }
    }
    __syncthreads();
#pragma unroll
    for (int pass = 0; pass < 4; ++pass) {
        int t = pass * 256 + tid;
        int r = t >> 4, seg = t & 15;
        int row = block0 + r;
        if (row < Pn) {
            bf16x8 o = *(const bf16x8*)(&Atile[r * 136 + seg * 8]);
            if (accum) {
                bf16x8 pv = *(const bf16x8*)(msgs + (size_t)row * Hdim + seg * 8);
#pragma unroll
                for (int j = 0; j < 8; ++j)
                    o[j] = (short)f2bf(bf2f((u16)o[j]) + bf2f((u16)pv[j]));
            }
            *(bf16x8*)(msgs + (size_t)row * Hdim + seg * 8) = o;
        }
    }
}

// out[row] = sigmoid( W_s2 . relu( (vs0[row]+msgs[row%Pn]) * W_s1^T + b_s1 ) + b_s2 )
__global__ __launch_bounds__(256) void final_kernel(
    const float* __restrict__ vs0, const u16* __restrict__ msgs, const u16* __restrict__ Bpack,
    const float* __restrict__ b_s1, const float* __restrict__ W_s2, const float* __restrict__ b_s2,
    float* __restrict__ out) {
    __shared__ __align__(16) u16 Atile[64 * 136];
    __shared__ __align__(16) u16 Btile[128 * 128];
    int tid = threadIdx.x;
    int block0 = blockIdx.x * 64;
    {
        const bf16x8* s = (const bf16x8*)Bpack;
        bf16x8* d = (bf16x8*)Btile;
#pragma unroll
        for (int i = 0; i < 8; ++i) d[tid + i * 256] = s[tid + i * 256];
    }
#pragma unroll
    for (int pass = 0; pass < 4; ++pass) {
        int t = pass * 256 + tid;
        int r = t >> 4, seg = t & 15;
        int row = block0 + r;
        int p = row % Pn;
        int co = seg * 8;
        const float* vp = vs0 + (size_t)row * Hdim + co;
        f32x4 x = *(const f32x4*)vp, y = *(const f32x4*)(vp + 4);
        bf16x8 m = *(const bf16x8*)(msgs + (size_t)p * Hdim + co);
        bf16x8 o;
#pragma unroll
        for (int j = 0; j < 4; ++j) {
            o[j] = (short)f2bf(x[j] + bf2f((u16)m[j]));
            o[j + 4] = (short)f2bf(y[j] + bf2f((u16)m[j + 4]));
        }
        *(bf16x8*)(&Atile[r * 136 + seg * 8]) = o;
    }
    __syncthreads();
    int w = tid >> 6, l = tid & 63;
    int arow = w * 16 + (l & 15);
    int kofs = (l >> 4) * 8;
    f32x4 acc[8];
#pragma unroll
    for (int nt = 0; nt < 8; ++nt) acc[nt] = (f32x4){0.f, 0.f, 0.f, 0.f};
#pragma unroll
    for (int ks = 0; ks < 4; ++ks) {
        bf16x8 af = *(const bf16x8*)(&Atile[arow * 136 + ks * 32 + kofs]);
#pragma unroll
        for (int nt = 0; nt < 8; ++nt) {
            bf16x8 bfr = *(const bf16x8*)(&Btile[((nt * 4 + ks) * 64 + l) * 8]);
            acc[nt] = __builtin_amdgcn_mfma_f32_16x16x32_bf16(af, bfr, acc[nt], 0, 0, 0);
        }
    }
    float part[4] = {0.f, 0.f, 0.f, 0.f};
#pragma unroll
    for (int nt = 0; nt < 8; ++nt) {
        int col = nt * 16 + (l & 15);
        float b1 = b_s1[col], w2 = W_s2[col];
#pragma unroll
        for (int reg = 0; reg < 4; ++reg)
            part[reg] += fmaxf(acc[nt][reg] + b1, 0.f) * w2;
    }
#pragma unroll
    for (int m = 1; m < 16; m <<= 1)
#pragma unroll
        for (int reg = 0; reg < 4; ++reg) part[reg] += __shfl_xor(part[reg], m, 64);
    if ((l & 15) == 0) {
        float lb = b_s2[0];
        int row0 = block0 + w * 16 + (l >> 4) * 4;
#pragma unroll
        for (int reg = 0; reg < 4; ++reg)
            out[row0 + reg] = 1.f / (1.f + expf(-(part[reg] + lb)));
    }
}

extern "C" void kernel_launch(void* const* d_in, const int* in_sizes, int n_in,
                              void* d_out, int out_size, void* d_ws, size_t ws_size,
                              hipStream_t stream) {
    (void)in_sizes; (void)n_in; (void)out_size; (void)ws_size;
    const int* ci = (const int*)d_in[0];
    const float* vs0 = (const float*)d_in[1];
    const float* W_vc = (const float*)d_in[2];
    const float* b_vc = (const float*)d_in[3];
    const float* W_ce = (const float*)d_in[4];
    const float* b_ce = (const float*)d_in[5];
    const float* W_cv = (const float*)d_in[6];
    const float* b_cv = (const float*)d_in[7];
    const float* W_s1 = (const float*)d_in[8];
    const float* b_s1 = (const float*)d_in[9];
    const float* W_s2 = (const float*)d_in[10];
    const float* b_s2 = (const float*)d_in[11];
    float* out = (float*)d_out;

    char* ws = (char*)d_ws;
    size_t off = 0;
    auto alloc = [&](size_t bytes) -> void* {
        off = (off + 255) & ~(size_t)255;
        void* p = ws + off;
        off += bytes;
        return p;
    };
    float* bias_comb = (float*)alloc(Hdim * 4);
    u16* WcombPack = (u16*)alloc(Hdim * Hdim * 2);
    u16* Ws1Pack = (u16*)alloc(Hdim * Hdim * 2);
    int* cursor = (int*)alloc(Pn * 4);
    int* entries = (int*)alloc((size_t)Pn * CAP * 4);       // 12.8 MB bucketed CSR
    u16* meanG = (u16*)alloc((size_t)NClause * Hdim * 2);   // 20.5 MB
    u16* V = (u16*)alloc((size_t)Pn * Hdim * 2);            // 12.8 MB aggregate (V1 carry)
    u16* msgs = (u16*)alloc((size_t)Pn * Hdim * 2);         // 12.8 MB

    // 1. fused setup: weight fold + both packs + bias + cursor zero
    setup_kernel<<<Hdim, Hdim, 0, stream>>>(W_vc, b_vc, W_ce, b_ce, W_cv, b_cv, W_s1,
                                            WcombPack, Ws1Pack, bias_comb, cursor);
    // 2. bucketed CSR
    fill_kernel<<<(NClause + 255) / 256, 256, 0, stream>>>(ci, cursor, entries);

    int gemm_grid = (Pn + 63) / 64;
    // 3-5. iter 1: meanG from fp32 vs0; V = agg; msgs1 = mask(W*V + b)
    cmean_kernel<<<NClause / 16, 256, 0, stream>>>(ci, vs0, nullptr, meanG, 1);
    vagg_kernel<<<(Pn + 3) / 4, 256, 0, stream>>>(meanG, cursor, entries, V, 0);
    gemm_kernel<<<gemm_grid, 256, 0, stream>>>(V, WcombPack, bias_comb, cursor, msgs, 0);
    // 6-8. iter 2: meanG from msgs1; V = V1 + agg; msgs2 = msgs1 + mask(W*V + b)
    cmean_kernel<<<NClause / 16, 256, 0, stream>>>(ci, nullptr, msgs, meanG, 0);
    vagg_kernel<<<(Pn + 3) / 4, 256, 0, stream>>>(meanG, cursor, entries, V, 1);
    gemm_kernel<<<gemm_grid, 256, 0, stream>>>(V, WcombPack, bias_comb, cursor, msgs, 1);
    // 9. readout
    final_kernel<<<NRows / 64, 256, 0, stream>>>(vs0, msgs, Ws1Pack, b_s1, W_s2, b_s2, out);
}

// Round 8
// 159.453 us; speedup vs baseline: 1.8599x; 1.1375x over previous
//
#include <hip/hip_runtime.h>
#include <math.h>

using u16 = unsigned short;
using u32 = unsigned int;

namespace {
constexpr int Hdim = 128;
constexpr int Pn = 50000;
constexpr int Cn = 20000;
constexpr int Bn = 4;
constexpr int NClause = Bn * Cn;   // 80000
constexpr int NRows = Bn * Pn;     // 200000
constexpr int CAP = 64;            // max clauses per variable (mean deg 4.8; P(>=64) ~ e^-150)
}

typedef __attribute__((ext_vector_type(4))) float f32x4;
typedef __attribute__((ext_vector_type(8))) short bf16x8;

static __device__ __forceinline__ float bf2f(u16 v) {
    u32 u = ((u32)v) << 16;
    return __builtin_bit_cast(float, u);
}
static __device__ __forceinline__ u16 f2bf(float f) {
    u32 u = __builtin_bit_cast(u32, f);
    u32 r = u + 0x7FFFu + ((u >> 16) & 1u);
    return (u16)(r >> 16);
}

// ONE setup kernel: redundant per-row weight-chain (no inter-stage sync), packs
// Wcomb & W_s1 into MFMA B-frag layout, folds bias, zeros cursor.
__global__ __launch_bounds__(128) void setup_kernel(
    const float* __restrict__ W_vc, const float* __restrict__ b_vc,
    const float* __restrict__ W_ce, const float* __restrict__ b_ce,
    const float* __restrict__ W_cv, const float* __restrict__ b_cv,
    const float* __restrict__ W_s1,
    u16* __restrict__ WcombPack, u16* __restrict__ Ws1Pack,
    float* __restrict__ bias_comb, int* __restrict__ cursor) {
    int o = blockIdx.x, t = threadIdx.x;
    __shared__ float u[Hdim];
    __shared__ float red[Hdim];
    float acc = 0.f;
#pragma unroll 8
    for (int h = 0; h < Hdim; ++h) acc = fmaf(W_cv[o * Hdim + h], W_ce[h * Hdim + t], acc);
    u[t] = acc;
    float b1 = b_ce[t];
#pragma unroll 8
    for (int h = 0; h < Hdim; ++h) b1 = fmaf(W_ce[t * Hdim + h], b_vc[h], b1);
    red[t] = W_cv[o * Hdim + t] * b1;
    __syncthreads();
#pragma unroll
    for (int s = 64; s > 0; s >>= 1) {
        if (t < s) red[t] += red[t + s];
        __syncthreads();
    }
    if (t == 0) bias_comb[o] = red[0] + b_cv[o];
    float w = 0.f;
#pragma unroll 8
    for (int h = 0; h < Hdim; ++h) w = fmaf(u[h], W_vc[h * Hdim + t], w);
    // pack element (n=o, k=t): dst[((nt*4+ks)*64 + lane)*8 + j], lane = lofs*16 + (n&15)
    int nt = o >> 4, ks = t >> 5, lofs = (t >> 3) & 3, j = t & 7;
    int lane = lofs * 16 + (o & 15);
    size_t dst = (size_t)(((nt * 4 + ks) * 64 + lane)) * 8 + j;
    WcombPack[dst] = f2bf(w);
    Ws1Pack[dst] = f2bf(W_s1[o * Hdim + t]);
    for (int i = o * 128 + t; i < Pn; i += 128 * 128) cursor[i] = 0;
}

// bucketed CSR: entries[p*CAP + pos] = fid, cursor[p] = degree (first-occurrence dedup)
__global__ void fill_kernel(const int* __restrict__ ci, int* __restrict__ cursor,
                            int* __restrict__ entries) {
    int fid = blockIdx.x * blockDim.x + threadIdx.x;
    if (fid >= NClause) return;
    int i0 = ci[fid * 3 + 0], i1 = ci[fid * 3 + 1], i2 = ci[fid * 3 + 2];
    int pos = atomicAdd(&cursor[i0], 1);
    entries[i0 * CAP + pos] = fid;
    if (i1 != i0) { pos = atomicAdd(&cursor[i1], 1); entries[i1 * CAP + pos] = fid; }
    if (i2 != i0 && i2 != i1) { pos = atomicAdd(&cursor[i2], 1); entries[i2 * CAP + pos] = fid; }
}

// Fused gather + mean + GEMM per clause:
//   M[fid] = bf16( W * mean3(rows) + (WITH_BIAS ? bias : 0) )
// iter1 (FROM_F32=1): rows from fp32 vs0[b*Pn + i]; iter2: rows from bf16 msgs[i].
template <int FROM_F32>
__global__ __launch_bounds__(256) void clause_kernel(
    const int* __restrict__ ci, const float* __restrict__ vs0, const u16* __restrict__ msgs,
    const u16* __restrict__ Bpack, const float* __restrict__ bias, u16* __restrict__ M) {
    __shared__ __align__(16) u16 Atile[64 * 136];   // 272B row pitch
    __shared__ __align__(16) u16 Btile[128 * 128];
    int tid = threadIdx.x;
    int block0 = blockIdx.x * 64;
    {   // stage packed B (32KB)
        const bf16x8* s = (const bf16x8*)Bpack;
        bf16x8* d = (bf16x8*)Btile;
#pragma unroll
        for (int i = 0; i < 8; ++i) d[tid + i * 256] = s[tid + i * 256];
    }
#pragma unroll
    for (int pass = 0; pass < 4; ++pass) {
        int t = pass * 256 + tid;
        int r = t >> 4, seg = t & 15;
        int fid = block0 + r;
        int i0 = ci[fid * 3 + 0], i1 = ci[fid * 3 + 1], i2 = ci[fid * 3 + 2];
        int co = seg * 8;
        float s[8];
        if (FROM_F32) {
            const float* base = vs0 + (size_t)(fid / Cn) * Pn * Hdim;
            const float* r0 = base + (size_t)i0 * Hdim + co;
            const float* r1 = base + (size_t)i1 * Hdim + co;
            const float* r2 = base + (size_t)i2 * Hdim + co;
            f32x4 a0 = *(const f32x4*)r0, a1 = *(const f32x4*)(r0 + 4);
            f32x4 b0 = *(const f32x4*)r1, b1 = *(const f32x4*)(r1 + 4);
            f32x4 c0 = *(const f32x4*)r2, c1 = *(const f32x4*)(r2 + 4);
#pragma unroll
            for (int j = 0; j < 4; ++j) {
                s[j] = a0[j] + b0[j] + c0[j];
                s[j + 4] = a1[j] + b1[j] + c1[j];
            }
        } else {
            bf16x8 v0 = *(const bf16x8*)(msgs + (size_t)i0 * Hdim + co);
            bf16x8 v1 = *(const bf16x8*)(msgs + (size_t)i1 * Hdim + co);
            bf16x8 v2 = *(const bf16x8*)(msgs + (size_t)i2 * Hdim + co);
#pragma unroll
            for (int j = 0; j < 8; ++j)
                s[j] = bf2f((u16)v0[j]) + bf2f((u16)v1[j]) + bf2f((u16)v2[j]);
        }
        bf16x8 o;
#pragma unroll
        for (int j = 0; j < 8; ++j) o[j] = (short)f2bf(s[j] * (1.f / 3.f));
        *(bf16x8*)(&Atile[r * 136 + seg * 8]) = o;
    }
    __syncthreads();
    int w = tid >> 6, l = tid & 63;
    int arow = w * 16 + (l & 15);
    int kofs = (l >> 4) * 8;
    f32x4 acc[8];
#pragma unroll
    for (int nt = 0; nt < 8; ++nt) acc[nt] = (f32x4){0.f, 0.f, 0.f, 0.f};
#pragma unroll
    for (int ks = 0; ks < 4; ++ks) {
        bf16x8 af = *(const bf16x8*)(&Atile[arow * 136 + ks * 32 + kofs]);
#pragma unroll
        for (int nt = 0; nt < 8; ++nt) {
            bf16x8 bfr = *(const bf16x8*)(&Btile[((nt * 4 + ks) * 64 + l) * 8]);
            acc[nt] = __builtin_amdgcn_mfma_f32_16x16x32_bf16(af, bfr, acc[nt], 0, 0, 0);
        }
    }
    __syncthreads();   // reuse Atile as output staging
    int crow = w * 16 + (l >> 4) * 4;
#pragma unroll
    for (int nt = 0; nt < 8; ++nt) {
        int col = nt * 16 + (l & 15);
        float bc = FROM_F32 ? bias[col] : 0.f;   // iter2: bias algebraically absorbed
#pragma unroll
        for (int reg = 0; reg < 4; ++reg)
            Atile[(crow + reg) * 136 + col] = f2bf(acc[nt][reg] + bc);
    }
    __syncthreads();
#pragma unroll
    for (int pass = 0; pass < 4; ++pass) {
        int t = pass * 256 + tid;
        int r = t >> 4, seg = t & 15;
        *(bf16x8*)(M + (size_t)(block0 + r) * Hdim + seg * 8) =
            *(const bf16x8*)(&Atile[r * 136 + seg * 8]);
    }
}

// iter1: msgs[p] = deg>0 ? (1/deg) sum M[fid] : 0           (= mask(W*V1 + b))
// iter2: msgs[p] = 2*msgs[p] + (deg>0 ? (1/deg) sum M[fid] : 0)
// 1 wave per variable: gathers need TLP, not LDS tiles.
__global__ __launch_bounds__(256) void var_kernel(const u16* __restrict__ M,
                                                  const int* __restrict__ counts,
                                                  const int* __restrict__ entries,
                                                  u16* __restrict__ msgs, int iter2) {
    int wave = threadIdx.x >> 6, lane = threadIdx.x & 63;
    int p = blockIdx.x * 4 + wave;
    if (p >= Pn) return;
    int deg = counts[p];
    const int* ep = entries + p * CAP;
    float a0 = 0.f, a1 = 0.f;
    for (int e = 0; e < deg; ++e) {
        int cid = ep[e];
        u32 v = *(const u32*)(M + (size_t)cid * Hdim + lane * 2);
        a0 += bf2f((u16)(v & 0xffffu));
        a1 += bf2f((u16)(v >> 16));
    }
    if (deg > 0) { float inv = 1.f / (float)deg; a0 *= inv; a1 *= inv; }
    u32* mp = (u32*)(msgs + (size_t)p * Hdim + lane * 2);
    if (iter2) {
        u32 old = *mp;
        a0 += 2.f * bf2f((u16)(old & 0xffffu));
        a1 += 2.f * bf2f((u16)(old >> 16));
    }
    *mp = (u32)f2bf(a0) | ((u32)f2bf(a1) << 16);
}

// out[row] = sigmoid( W_s2 . relu( (vs0[row]+msgs[row%Pn]) * W_s1^T + b_s1 ) + b_s2 )
__global__ __launch_bounds__(256) void final_kernel(
    const float* __restrict__ vs0, const u16* __restrict__ msgs, const u16* __restrict__ Bpack,
    const float* __restrict__ b_s1, const float* __restrict__ W_s2, const float* __restrict__ b_s2,
    float* __restrict__ out) {
    __shared__ __align__(16) u16 Atile[64 * 136];
    __shared__ __align__(16) u16 Btile[128 * 128];
    int tid = threadIdx.x;
    int block0 = blockIdx.x * 64;
    {
        const bf16x8* s = (const bf16x8*)Bpack;
        bf16x8* d = (bf16x8*)Btile;
#pragma unroll
        for (int i = 0; i < 8; ++i) d[tid + i * 256] = s[tid + i * 256];
    }
#pragma unroll
    for (int pass = 0; pass < 4; ++pass) {
        int t = pass * 256 + tid;
        int r = t >> 4, seg = t & 15;
        int row = block0 + r;
        int p = row % Pn;
        int co = seg * 8;
        const float* vp = vs0 + (size_t)row * Hdim + co;
        f32x4 x = *(const f32x4*)vp, y = *(const f32x4*)(vp + 4);
        bf16x8 m = *(const bf16x8*)(msgs + (size_t)p * Hdim + co);
        bf16x8 o;
#pragma unroll
        for (int j = 0; j < 4; ++j) {
            o[j] = (short)f2bf(x[j] + bf2f((u16)m[j]));
            o[j + 4] = (short)f2bf(y[j] + bf2f((u16)m[j + 4]));
        }
        *(bf16x8*)(&Atile[r * 136 + seg * 8]) = o;
    }
    __syncthreads();
    int w = tid >> 6, l = tid & 63;
    int arow = w * 16 + (l & 15);
    int kofs = (l >> 4) * 8;
    f32x4 acc[8];
#pragma unroll
    for (int nt = 0; nt < 8; ++nt) acc[nt] = (f32x4){0.f, 0.f, 0.f, 0.f};
#pragma unroll
    for (int ks = 0; ks < 4; ++ks) {
        bf16x8 af = *(const bf16x8*)(&Atile[arow * 136 + ks * 32 + kofs]);
#pragma unroll
        for (int nt = 0; nt < 8; ++nt) {
            bf16x8 bfr = *(const bf16x8*)(&Btile[((nt * 4 + ks) * 64 + l) * 8]);
            acc[nt] = __builtin_amdgcn_mfma_f32_16x16x32_bf16(af, bfr, acc[nt], 0, 0, 0);
        }
    }
    float part[4] = {0.f, 0.f, 0.f, 0.f};
#pragma unroll
    for (int nt = 0; nt < 8; ++nt) {
        int col = nt * 16 + (l & 15);
        float b1 = b_s1[col], w2 = W_s2[col];
#pragma unroll
        for (int reg = 0; reg < 4; ++reg)
            part[reg] += fmaxf(acc[nt][reg] + b1, 0.f) * w2;
    }
#pragma unroll
    for (int m = 1; m < 16; m <<= 1)
#pragma unroll
        for (int reg = 0; reg < 4; ++reg) part[reg] += __shfl_xor(part[reg], m, 64);
    if ((l & 15) == 0) {
        float lb = b_s2[0];
        int row0 = block0 + w * 16 + (l >> 4) * 4;
#pragma unroll
        for (int reg = 0; reg < 4; ++reg)
            out[row0 + reg] = 1.f / (1.f + expf(-(part[reg] + lb)));
    }
}

extern "C" void kernel_launch(void* const* d_in, const int* in_sizes, int n_in,
                              void* d_out, int out_size, void* d_ws, size_t ws_size,
                              hipStream_t stream) {
    (void)in_sizes; (void)n_in; (void)out_size; (void)ws_size;
    const int* ci = (const int*)d_in[0];
    const float* vs0 = (const float*)d_in[1];
    const float* W_vc = (const float*)d_in[2];
    const float* b_vc = (const float*)d_in[3];
    const float* W_ce = (const float*)d_in[4];
    const float* b_ce = (const float*)d_in[5];
    const float* W_cv = (const float*)d_in[6];
    const float* b_cv = (const float*)d_in[7];
    const float* W_s1 = (const float*)d_in[8];
    const float* b_s1 = (const float*)d_in[9];
    const float* W_s2 = (const float*)d_in[10];
    const float* b_s2 = (const float*)d_in[11];
    float* out = (float*)d_out;

    char* ws = (char*)d_ws;
    size_t off = 0;
    auto alloc = [&](size_t bytes) -> void* {
        off = (off + 255) & ~(size_t)255;
        void* p = ws + off;
        off += bytes;
        return p;
    };
    float* bias_comb = (float*)alloc(Hdim * 4);
    u16* WcombPack = (u16*)alloc(Hdim * Hdim * 2);
    u16* Ws1Pack = (u16*)alloc(Hdim * Hdim * 2);
    int* cursor = (int*)alloc(Pn * 4);
    int* entries = (int*)alloc((size_t)Pn * CAP * 4);       // 12.8 MB bucketed CSR
    u16* M = (u16*)alloc((size_t)NClause * Hdim * 2);       // 20.5 MB per-clause messages
    u16* msgs = (u16*)alloc((size_t)Pn * Hdim * 2);         // 12.8 MB

    // 1. fused setup: weight fold + both packs + bias + cursor zero
    setup_kernel<<<Hdim, Hdim, 0, stream>>>(W_vc, b_vc, W_ce, b_ce, W_cv, b_cv, W_s1,
                                            WcombPack, Ws1Pack, bias_comb, cursor);
    // 2. bucketed CSR
    fill_kernel<<<(NClause + 255) / 256, 256, 0, stream>>>(ci, cursor, entries);

    // 3-4. iter 1: M = W*mean3(vs0) + b per clause; msgs1 = masked mean over buckets
    clause_kernel<1><<<NClause / 64, 256, 0, stream>>>(ci, vs0, nullptr, WcombPack, bias_comb, M);
    var_kernel<<<(Pn + 3) / 4, 256, 0, stream>>>(M, cursor, entries, msgs, 0);
    // 5-6. iter 2: M2 = W*mean3(msgs1) per clause; msgs2 = 2*msgs1 + masked mean
    clause_kernel<0><<<NClause / 64, 256, 0, stream>>>(ci, nullptr, msgs, WcombPack, bias_comb, M);
    var_kernel<<<(Pn + 3) / 4, 256, 0, stream>>>(M, cursor, entries, msgs, 1);
    // 7. readout
    final_kernel<<<NRows / 64, 256, 0, stream>>>(vs0, msgs, Ws1Pack, b_s1, W_s2, b_s2, out);
}